// Round 3
// baseline (1035.095 us; speedup 1.0000x reference)
//
#include <hip/hip_runtime.h>
#include <math.h>

typedef unsigned short u16;
typedef __bf16 bf16x8 __attribute__((ext_vector_type(8)));
typedef float f32x4 __attribute__((ext_vector_type(4)));
typedef unsigned short u16x8 __attribute__((ext_vector_type(8)));
typedef unsigned short u16x4 __attribute__((ext_vector_type(4)));

#define H 2048
#define LSEQ 1024
#define LP (LSEQ+3)

__device__ __forceinline__ float bf2f(u16 u) {
    union { float f; unsigned int i; } x; x.i = ((unsigned int)u) << 16; return x.f;
}
__device__ __forceinline__ u16 f2bf(float f) {
    union { float f; unsigned int i; } x; x.f = f;
    unsigned int r = x.i + 0x7fffu + ((x.i >> 16) & 1u);
    return (u16)(r >> 16);
}

enum { EPI_XZ = 0, EPI_CONV = 1, EPI_DBC = 2, EPI_OUT = 3, EPI_DELTA = 4 };

// C[m,n] = sum_tap A_tap[m,:] . B_tap[n,:]   (A,B bf16, K-contiguous, row stride K)
// BM=BN=128, BK=32, 256 threads = 4 waves, each wave a 64x64 quadrant (4x4 MFMA tiles).
template<int EPI, int NTAP>
__launch_bounds__(256)
__global__ void gemm_bt(const u16* __restrict__ A, const u16* __restrict__ B,
                        int K, long aTapStride, long bTapStride,
                        void* __restrict__ out0, void* __restrict__ out1,
                        const float* __restrict__ bias, const float* __restrict__ resid) {
    __shared__ u16 As[128 * 32];
    __shared__ u16 Bs[128 * 32];
    const int m0 = blockIdx.x * 128;
    const int n0 = blockIdx.y * 128;
    const int tid = threadIdx.x;
    const int lane = tid & 63;
    const int w = tid >> 6;
    const int wr = w >> 1, wc = w & 1;
    const int scol = (tid & 3) * 8;
    const int r0 = tid >> 2;

    long abase;
    if (EPI == EPI_CONV) {
        int b = m0 >> 10, l0 = m0 & 1023;
        abase = (long)(b * LP + l0) * K;
    } else {
        abase = (long)m0 * K;
    }
    const u16* Bt = B + (long)n0 * K;

    f32x4 acc[4][4];
#pragma unroll
    for (int i = 0; i < 4; i++)
#pragma unroll
        for (int j = 0; j < 4; j++) acc[i][j] = (f32x4){0.f, 0.f, 0.f, 0.f};

    const int kIters = K / 32;
    for (int tap = 0; tap < NTAP; ++tap) {
        const u16* Ag = A + abase + (long)tap * aTapStride;
        const u16* Bg = Bt + (long)tap * bTapStride;
        for (int kt = 0; kt < kIters; ++kt) {
            const int k0 = kt * 32;
            u16x8 av0 = *(const u16x8*)(Ag + (long)r0 * K + k0 + scol);
            u16x8 bv0 = *(const u16x8*)(Bg + (long)r0 * K + k0 + scol);
            u16x8 av1 = *(const u16x8*)(Ag + (long)(r0 + 64) * K + k0 + scol);
            u16x8 bv1 = *(const u16x8*)(Bg + (long)(r0 + 64) * K + k0 + scol);
            __syncthreads();
            *(u16x8*)&As[tid * 8] = av0;
            *(u16x8*)&Bs[tid * 8] = bv0;
            *(u16x8*)&As[(256 + tid) * 8] = av1;
            *(u16x8*)&Bs[(256 + tid) * 8] = bv1;
            __syncthreads();
            bf16x8 af[4], bfr[4];
#pragma unroll
            for (int i = 0; i < 4; i++) {
                const int row = wr * 64 + i * 16 + (lane & 15);
                af[i] = *(const bf16x8*)&As[row * 32 + (lane >> 4) * 8];
            }
#pragma unroll
            for (int j = 0; j < 4; j++) {
                const int row = wc * 64 + j * 16 + (lane & 15);
                bfr[j] = *(const bf16x8*)&Bs[row * 32 + (lane >> 4) * 8];
            }
#pragma unroll
            for (int i = 0; i < 4; i++)
#pragma unroll
                for (int j = 0; j < 4; j++)
                    acc[i][j] = __builtin_amdgcn_mfma_f32_16x16x32_bf16(af[i], bfr[j], acc[i][j], 0, 0, 0);
        }
    }

#pragma unroll
    for (int i = 0; i < 4; i++) {
#pragma unroll
        for (int j = 0; j < 4; j++) {
#pragma unroll
            for (int r = 0; r < 4; r++) {
                const int m = m0 + wr * 64 + i * 16 + ((lane >> 4) << 2) + r;
                const int n = n0 + wc * 64 + j * 16 + (lane & 15);
                float v = acc[i][j][r];
                if constexpr (EPI == EPI_XZ) {
                    const int b = m >> 10, l = m & 1023;
                    if (n < H) ((u16*)out0)[((long)(b * LP + l + 3)) * H + n] = f2bf(v);
                    else       ((u16*)out1)[(long)m * H + (n - H)] = f2bf(v);
                } else if constexpr (EPI == EPI_CONV) {
                    v += bias[n];
                    v = v / (1.f + expf(-v));   // silu
                    ((u16*)out0)[(long)m * H + n] = f2bf(v);
                } else if constexpr (EPI == EPI_DBC) {
                    if (n < 96) ((float*)out0)[(long)m * 96 + n] = v;
                    if (n < 64) ((u16*)out1)[(long)m * 64 + n] = f2bf(v);
                } else if constexpr (EPI == EPI_DELTA) {
                    v += bias[n];
                    v = (v > 20.f) ? v : log1pf(expf(v));   // softplus
                    ((float*)out0)[(long)m * H + n] = v;
                } else {
                    ((float*)out0)[(long)m * H + n] = v + resid[(long)m * H + n];
                }
            }
        }
    }
}

// conv_w (tap,i,o) fp32 -> Wt (tap,o,i) bf16
__global__ void transpose_w(const float* __restrict__ in, u16* __restrict__ out) {
    __shared__ u16 s[64][72];
    const int tap = blockIdx.z;
    const long base = (long)tap * H * H;
    const int i0 = blockIdx.x * 64, o0 = blockIdx.y * 64;
    const int r = threadIdx.x >> 3;
    const int c = (threadIdx.x & 7) * 8;
#pragma unroll
    for (int rr = r; rr < 64; rr += 32) {
        f32x4 a = *(const f32x4*)&in[base + (long)(i0 + rr) * H + o0 + c];
        f32x4 b = *(const f32x4*)&in[base + (long)(i0 + rr) * H + o0 + c + 4];
#pragma unroll
        for (int j = 0; j < 4; j++) { s[rr][c + j] = f2bf(a[j]); s[rr][c + 4 + j] = f2bf(b[j]); }
    }
    __syncthreads();
#pragma unroll
    for (int rr = r; rr < 64; rr += 32) {
        u16x8 v;
#pragma unroll
        for (int j = 0; j < 8; j++) v[j] = s[c + j][rr];
        *(u16x8*)&out[base + (long)(o0 + rr) * H + i0 + c] = v;
    }
}

__global__ void cast_f2b_k(const float* __restrict__ in, u16* __restrict__ out) {
    const long i = ((long)blockIdx.x * 256 + threadIdx.x) * 4;
    f32x4 v = *(const f32x4*)(in + i);
    u16x4 o;
#pragma unroll
    for (int j = 0; j < 4; j++) o[j] = f2bf(v[j]);
    *(u16x4*)(out + i) = o;
}

__global__ void pad_zero_k(u16* __restrict__ xcp) {
    const int i = blockIdx.x * 256 + threadIdx.x;   // 2*3*H total
    const int b = i / (3 * H);
    const int r = i - b * 3 * H;
    xcp[(long)b * LP * H + r] = 0;
}

// x_proj (96 x 2048 fp32) -> bf16 padded to 128 rows
__global__ void xpw_k(const float* __restrict__ xp, u16* __restrict__ out) {
    const int i = blockIdx.x * 256 + threadIdx.x;   // 128*H
    const int r = i >> 11;
    out[i] = (r < 96) ? f2bf(xp[i]) : (u16)0;
}

__global__ void rmsnorm_k(const float* __restrict__ x, const float* __restrict__ w, u16* __restrict__ h) {
    const long base = (long)blockIdx.x * H;
    const int tid = threadIdx.x;
    f32x4 a = *(const f32x4*)&x[base + tid * 8];
    f32x4 b = *(const f32x4*)&x[base + tid * 8 + 4];
    float f[8];
    float ss = 0.f;
#pragma unroll
    for (int j = 0; j < 4; j++) { f[j] = a[j]; f[4 + j] = b[j]; }
#pragma unroll
    for (int j = 0; j < 8; j++) ss += f[j] * f[j];
#pragma unroll
    for (int m = 32; m > 0; m >>= 1) ss += __shfl_down(ss, m);
    __shared__ float red[4];
    if ((tid & 63) == 0) red[tid >> 6] = ss;
    __syncthreads();
    ss = red[0] + red[1] + red[2] + red[3];
    const float scale = rsqrtf(ss * (1.f / H) + 1e-5f);
    f32x4 wa = *(const f32x4*)&w[tid * 8];
    f32x4 wb = *(const f32x4*)&w[tid * 8 + 4];
    u16x8 o;
#pragma unroll
    for (int j = 0; j < 4; j++) { o[j] = f2bf(f[j] * scale * wa[j]); o[4 + j] = f2bf(f[4 + j] * scale * wb[j]); }
    *(u16x8*)&h[base + tid * 8] = o;
}

// one thread per (b,h,n): n = lane&15; shuffle-reduce over n; lane n==0 writes y
__global__ void scan_k(const float* __restrict__ delta, const u16* __restrict__ xc,
                       const float* __restrict__ dbc, const float* __restrict__ alog,
                       const float* __restrict__ dvec, u16* __restrict__ ybuf) {
    const int tid = threadIdx.x;
    const int n = tid & 15;
    const int ch = blockIdx.x * 16 + (tid >> 4);
    const int b = ch >> 11, hh = ch & 2047;
    const float An = -expf(alog[hh * 16 + n]);
    const float Dh = dvec[hh];
    float s = 0.f;
    const long tokbase = (long)b * LSEQ;
    for (int t = 0; t < LSEQ; t++) {
        const long tt = tokbase + t;
        const float dl = delta[tt * H + hh];
        const float xv = bf2f(xc[tt * H + hh]);
        const float Bn = dbc[tt * 96 + 64 + n];
        const float Cn = dbc[tt * 96 + 80 + n];
        const float e = expf(dl * An);
        s = e * s + dl * xv * Bn;
        float p = s * Cn;
        p += __shfl_xor(p, 1);
        p += __shfl_xor(p, 2);
        p += __shfl_xor(p, 4);
        p += __shfl_xor(p, 8);
        if (n == 0) ybuf[tt * H + hh] = f2bf(p + Dh * xv);
    }
}

__global__ void gate_k(u16* __restrict__ y, const u16* __restrict__ z) {
    const long i8 = ((long)blockIdx.x * 256 + threadIdx.x) * 8;
    u16x8 yv = *(u16x8*)&y[i8];
    u16x8 zv = *(const u16x8*)&z[i8];
#pragma unroll
    for (int j = 0; j < 8; j++) {
        const float zf = bf2f(zv[j]);
        const float g = zf / (1.f + expf(-zf));
        yv[j] = f2bf(bf2f(yv[j]) * g);
    }
    *(u16x8*)&y[i8] = yv;
}

extern "C" void kernel_launch(void* const* d_in, const int* in_sizes, int n_in,
                              void* d_out, int out_size, void* d_ws, size_t ws_size,
                              hipStream_t stream) {
    const float* x       = (const float*)d_in[0];
    const float* norm_w  = (const float*)d_in[1];
    const float* in_proj = (const float*)d_in[2];
    const float* conv_w  = (const float*)d_in[3];
    const float* conv_b  = (const float*)d_in[4];
    const float* x_proj  = (const float*)d_in[5];
    const float* dt_w    = (const float*)d_in[6];
    const float* dt_b    = (const float*)d_in[7];
    const float* a_log   = (const float*)d_in[8];
    const float* Dv      = (const float*)d_in[9];
    const float* out_w   = (const float*)d_in[10];
    float* out = (float*)d_out;

    // Workspace layout (77.2 MB), lifetimes annotated:
    char* ws = (char*)d_ws;
    u16*   xcp    = (u16*)(ws);                   //  8,413,184  padded conv input (bf16)
    u16*   hy     = (u16*)(ws + 8413184);         //  8,388,608  h -> xcc
    u16*   z_buf  = (u16*)(ws + 16801792);        //  8,388,608
    u16*   wt     = (u16*)(ws + 25190400);        // 33,554,432  conv_w^T bf16 (dead after conv)
    float* dlt    = (float*)(ws + 25190400);      // 16,777,216  aliases wt (after conv)
    u16*   y_buf  = (u16*)(ws + 41967616);        //  8,388,608  aliases wt tail
    u16*   inw    = (u16*)(ws + 58744832);        // 16,777,216  in_proj bf16 (dead after XZ)
    u16*   outw   = (u16*)(ws + 58744832);        //  8,388,608  out_proj bf16 (cast after XZ)
    u16*   xpw    = (u16*)(ws + 75522048);        //    524,288  x_proj bf16 padded
    float* dbc    = (float*)(ws + 76046336);      //    786,432  fp32 (T x 96)
    u16*   dbc64  = (u16*)(ws + 76832768);        //    262,144  bf16 delta cols
    u16*   dtw    = (u16*)(ws + 77094912);        //    131,072  dt_proj_w bf16
    // total 77,225,984 bytes

    transpose_w<<<dim3(32, 32, 4), 256, 0, stream>>>(conv_w, wt);
    pad_zero_k<<<48, 256, 0, stream>>>(xcp);
    xpw_k<<<1024, 256, 0, stream>>>(x_proj, xpw);
    cast_f2b_k<<<8192, 256, 0, stream>>>(in_proj, inw);     // 8,388,608 elems
    cast_f2b_k<<<128, 256, 0, stream>>>(dt_w, dtw);         //   131,072 elems
    rmsnorm_k<<<2048, 256, 0, stream>>>(x, norm_w, hy);

    // xz = h @ in_proj_w.T : split into xc (padded) and z
    gemm_bt<EPI_XZ, 1><<<dim3(16, 32), 256, 0, stream>>>(
        hy, inw, 2048, 0, 0, xcp, z_buf, nullptr, nullptr);

    // out_proj cast (reuses inw region; safe: after XZ on same stream)
    cast_f2b_k<<<4096, 256, 0, stream>>>(out_w, outw);      // 4,194,304 elems

    // conv (4 taps) + bias + silu -> xcc (hy region)
    gemm_bt<EPI_CONV, 4><<<dim3(16, 16), 256, 0, stream>>>(
        xcp, wt, 2048, H, (long)H * H, hy, nullptr, conv_b, nullptr);

    // dBC = xc @ x_proj_w.T (fp32 out + bf16 copy of delta cols)
    gemm_bt<EPI_DBC, 1><<<dim3(16, 1), 256, 0, stream>>>(
        hy, xpw, 2048, 0, 0, dbc, dbc64, nullptr, nullptr);

    // delta = softplus(dbc64 @ dt_proj_w.T + dt_b)  (K=64, fp32 out into dead wt region)
    gemm_bt<EPI_DELTA, 1><<<dim3(16, 16), 256, 0, stream>>>(
        dbc64, dtw, 64, 0, 0, dlt, nullptr, dt_b, nullptr);

    // selective scan -> y
    scan_k<<<256, 256, 0, stream>>>(dlt, hy, dbc, a_log, Dv, y_buf);
    gate_k<<<2048, 256, 0, stream>>>(y_buf, z_buf);

    // out = x + yg @ out_proj_w.T  (fp32 output)
    gemm_bt<EPI_OUT, 1><<<dim3(16, 16), 256, 0, stream>>>(
        y_buf, outw, 2048, 0, 0, out, nullptr, nullptr, x);
}

// Round 4
// 726.868 us; speedup vs baseline: 1.4240x; 1.4240x over previous
//
#include <hip/hip_runtime.h>
#include <math.h>

typedef unsigned short u16;
typedef __bf16 bf16x8 __attribute__((ext_vector_type(8)));
typedef float f32x4 __attribute__((ext_vector_type(4)));
typedef unsigned short u16x8 __attribute__((ext_vector_type(8)));
typedef unsigned short u16x4 __attribute__((ext_vector_type(4)));

#define H 2048
#define LSEQ 1024
#define LP (LSEQ+3)
#define NC 16
#define CL 64

__device__ __forceinline__ float bf2f(u16 u) {
    union { float f; unsigned int i; } x; x.i = ((unsigned int)u) << 16; return x.f;
}
__device__ __forceinline__ u16 f2bf(float f) {
    union { float f; unsigned int i; } x; x.f = f;
    unsigned int r = x.i + 0x7fffu + ((x.i >> 16) & 1u);
    return (u16)(r >> 16);
}

__device__ __forceinline__ void gload_lds16(const void* g, void* l) {
    __builtin_amdgcn_global_load_lds((const __attribute__((address_space(1))) void*)g,
                                     (__attribute__((address_space(3))) void*)l,
                                     16, 0, 0);
}

enum { EPI_XZ = 0, EPI_CONV = 1, EPI_DBC = 2, EPI_OUT = 3, EPI_DELTA = 4 };

// C[m,n] = sum_tap A_tap[m,:] . B_tap[n,:]   (A,B bf16, K-contiguous, row stride K)
// BM=BN=128, BK=32, 256 threads = 4 waves, 64x64 per wave (4x4 MFMA tiles).
// global_load_lds width-16 staging (m97 pattern).
template<int EPI, int NTAP>
__launch_bounds__(256)
__global__ void gemm_bt(const u16* __restrict__ A, const u16* __restrict__ B,
                        int K, long aTapStride, long bTapStride,
                        void* __restrict__ out0, void* __restrict__ out1,
                        const float* __restrict__ bias, const float* __restrict__ resid) {
    __shared__ u16 As[128 * 32];
    __shared__ u16 Bs[128 * 32];
    const int m0 = blockIdx.x * 128;
    const int n0 = blockIdx.y * 128;
    const int tid = threadIdx.x;
    const int lane = tid & 63;
    const int w = tid >> 6;
    const int wr = w >> 1, wc = w & 1;
    const int scol = (tid & 3) * 8;

    long abase;
    if (EPI == EPI_CONV) {
        int b = m0 >> 10, l0 = m0 & 1023;
        abase = (long)(b * LP + l0) * K;
    } else {
        abase = (long)m0 * K;
    }
    const u16* Bt = B + (long)n0 * K;

    f32x4 acc[4][4];
#pragma unroll
    for (int i = 0; i < 4; i++)
#pragma unroll
        for (int j = 0; j < 4; j++) acc[i][j] = (f32x4){0.f, 0.f, 0.f, 0.f};

    const int kIters = K / 32;
    for (int tap = 0; tap < NTAP; ++tap) {
        const u16* Ag = A + abase + (long)tap * aTapStride;
        const u16* Bg = Bt + (long)tap * bTapStride;
        for (int kt = 0; kt < kIters; ++kt) {
            const int k0 = kt * 32;
            __syncthreads();
#pragma unroll
            for (int j = 0; j < 2; j++) {
                const int idx = j * 256 + tid;
                const int r = idx >> 2;
                gload_lds16(Ag + (long)r * K + k0 + scol, &As[idx * 8]);
                gload_lds16(Bg + (long)r * K + k0 + scol, &Bs[idx * 8]);
            }
            __syncthreads();
            bf16x8 af[4], bfr[4];
#pragma unroll
            for (int i = 0; i < 4; i++) {
                const int row = wr * 64 + i * 16 + (lane & 15);
                af[i] = *(const bf16x8*)&As[row * 32 + (lane >> 4) * 8];
            }
#pragma unroll
            for (int j = 0; j < 4; j++) {
                const int row = wc * 64 + j * 16 + (lane & 15);
                bfr[j] = *(const bf16x8*)&Bs[row * 32 + (lane >> 4) * 8];
            }
#pragma unroll
            for (int i = 0; i < 4; i++)
#pragma unroll
                for (int j = 0; j < 4; j++)
                    acc[i][j] = __builtin_amdgcn_mfma_f32_16x16x32_bf16(af[i], bfr[j], acc[i][j], 0, 0, 0);
        }
    }

#pragma unroll
    for (int i = 0; i < 4; i++) {
#pragma unroll
        for (int j = 0; j < 4; j++) {
#pragma unroll
            for (int r = 0; r < 4; r++) {
                const int m = m0 + wr * 64 + i * 16 + ((lane >> 4) << 2) + r;
                const int n = n0 + wc * 64 + j * 16 + (lane & 15);
                float v = acc[i][j][r];
                if constexpr (EPI == EPI_XZ) {
                    const int b = m >> 10, l = m & 1023;
                    if (n < H) ((u16*)out0)[((long)(b * LP + l + 3)) * H + n] = f2bf(v);
                    else       ((u16*)out1)[(long)m * H + (n - H)] = f2bf(v);
                } else if constexpr (EPI == EPI_CONV) {
                    v += bias[n];
                    v = v / (1.f + expf(-v));   // silu
                    ((u16*)out0)[(long)m * H + n] = f2bf(v);
                } else if constexpr (EPI == EPI_DBC) {
                    if (n < 96) ((float*)out0)[(long)m * 96 + n] = v;
                    if (n < 64) ((u16*)out1)[(long)m * 64 + n] = f2bf(v);
                } else if constexpr (EPI == EPI_DELTA) {
                    v += bias[n];
                    v = (v > 20.f) ? v : log1pf(expf(v));   // softplus
                    ((float*)out0)[(long)m * H + n] = v;
                } else {
                    ((float*)out0)[(long)m * H + n] = v + resid[(long)m * H + n];
                }
            }
        }
    }
}

// conv_w (tap,i,o) fp32 -> Wt (tap,o,i) bf16
__global__ void transpose_w(const float* __restrict__ in, u16* __restrict__ out) {
    __shared__ u16 s[64][72];
    const int tap = blockIdx.z;
    const long base = (long)tap * H * H;
    const int i0 = blockIdx.x * 64, o0 = blockIdx.y * 64;
    const int r = threadIdx.x >> 3;
    const int c = (threadIdx.x & 7) * 8;
#pragma unroll
    for (int rr = r; rr < 64; rr += 32) {
        f32x4 a = *(const f32x4*)&in[base + (long)(i0 + rr) * H + o0 + c];
        f32x4 b = *(const f32x4*)&in[base + (long)(i0 + rr) * H + o0 + c + 4];
#pragma unroll
        for (int j = 0; j < 4; j++) { s[rr][c + j] = f2bf(a[j]); s[rr][c + 4 + j] = f2bf(b[j]); }
    }
    __syncthreads();
#pragma unroll
    for (int rr = r; rr < 64; rr += 32) {
        u16x8 v;
#pragma unroll
        for (int j = 0; j < 8; j++) v[j] = s[c + j][rr];
        *(u16x8*)&out[base + (long)(o0 + rr) * H + i0 + c] = v;
    }
}

__global__ void cast_f2b_k(const float* __restrict__ in, u16* __restrict__ out) {
    const long i = ((long)blockIdx.x * 256 + threadIdx.x) * 4;
    f32x4 v = *(const f32x4*)(in + i);
    u16x4 o;
#pragma unroll
    for (int j = 0; j < 4; j++) o[j] = f2bf(v[j]);
    *(u16x4*)(out + i) = o;
}

__global__ void pad_zero_k(u16* __restrict__ xcp) {
    const int i = blockIdx.x * 256 + threadIdx.x;   // 2*3*H total
    const int b = i / (3 * H);
    const int r = i - b * 3 * H;
    xcp[(long)b * LP * H + r] = 0;
}

// x_proj (96 x 2048 fp32) -> bf16 padded to 128 rows
__global__ void xpw_k(const float* __restrict__ xp, u16* __restrict__ out) {
    const int i = blockIdx.x * 256 + threadIdx.x;   // 128*H
    const int r = i >> 11;
    out[i] = (r < 96) ? f2bf(xp[i]) : (u16)0;
}

__global__ void rmsnorm_k(const float* __restrict__ x, const float* __restrict__ w, u16* __restrict__ h) {
    const long base = (long)blockIdx.x * H;
    const int tid = threadIdx.x;
    f32x4 a = *(const f32x4*)&x[base + tid * 8];
    f32x4 b = *(const f32x4*)&x[base + tid * 8 + 4];
    float f[8];
    float ss = 0.f;
#pragma unroll
    for (int j = 0; j < 4; j++) { f[j] = a[j]; f[4 + j] = b[j]; }
#pragma unroll
    for (int j = 0; j < 8; j++) ss += f[j] * f[j];
#pragma unroll
    for (int m = 32; m > 0; m >>= 1) ss += __shfl_down(ss, m);
    __shared__ float red[4];
    if ((tid & 63) == 0) red[tid >> 6] = ss;
    __syncthreads();
    ss = red[0] + red[1] + red[2] + red[3];
    const float scale = rsqrtf(ss * (1.f / H) + 1e-5f);
    f32x4 wa = *(const f32x4*)&w[tid * 8];
    f32x4 wb = *(const f32x4*)&w[tid * 8 + 4];
    u16x8 o;
#pragma unroll
    for (int j = 0; j < 4; j++) { o[j] = f2bf(f[j] * scale * wa[j]); o[4 + j] = f2bf(f[4 + j] * scale * wb[j]); }
    *(u16x8*)&h[base + tid * 8] = o;
}

// Chunked scan, one block per (b,h) channel. 256 threads = (chunk c = tid>>4) x (state n = tid&15).
// Phase A: local scan of 64-step chunk -> (prod e, local state). Phase B: 16-step scan of chunk
// summaries in LDS. Phase C: re-scan chunk from prefix, y = (sum_n s*C + D*x) * silu(z).
__launch_bounds__(256)
__global__ void scan_fused_k(const float* __restrict__ delta, const u16* __restrict__ xc,
                             const float* __restrict__ dbc, const float* __restrict__ alog,
                             const float* __restrict__ dvec, const u16* __restrict__ z,
                             u16* __restrict__ ybuf) {
    __shared__ float sa[256];
    __shared__ float sl[256];
    const int tid = threadIdx.x;
    const int n = tid & 15;
    const int c = tid >> 4;
    const int ch = blockIdx.x;
    const int b = ch >> 11, hh = ch & 2047;
    const float An = -expf(alog[hh * 16 + n]);
    const float Dh = dvec[hh];
    const long tok0 = (long)b * LSEQ + c * CL;

    float s = 0.f, ap = 1.f;
    for (int j = 0; j < CL; j++) {
        const long tt = tok0 + j;
        const float dl = delta[tt * H + hh];
        const float xv = bf2f(xc[tt * H + hh]);
        const float Bn = dbc[tt * 96 + 64 + n];
        const float e = expf(dl * An);
        s = e * s + dl * xv * Bn;
        ap *= e;
    }
    sa[tid] = ap;
    sl[tid] = s;
    __syncthreads();
    if (tid < 16) {     // c == 0, n == tid
        float S = 0.f;
        for (int cc = 0; cc < NC; cc++) {
            const int idx = cc * 16 + tid;
            const float a = sa[idx], sloc = sl[idx];
            sa[idx] = S;                    // prefix state entering chunk cc
            S = a * S + sloc;
        }
    }
    __syncthreads();
    s = sa[tid];
    for (int j = 0; j < CL; j++) {
        const long tt = tok0 + j;
        const float dl = delta[tt * H + hh];
        const float xv = bf2f(xc[tt * H + hh]);
        const float Bn = dbc[tt * 96 + 64 + n];
        const float Cn = dbc[tt * 96 + 80 + n];
        const float e = expf(dl * An);
        s = e * s + dl * xv * Bn;
        float p = s * Cn;
        p += __shfl_xor(p, 1);
        p += __shfl_xor(p, 2);
        p += __shfl_xor(p, 4);
        p += __shfl_xor(p, 8);
        if (n == 0) {
            const float zf = bf2f(z[tt * H + hh]);
            const float g = zf / (1.f + expf(-zf));
            ybuf[tt * H + hh] = f2bf((p + Dh * xv) * g);
        }
    }
}

extern "C" void kernel_launch(void* const* d_in, const int* in_sizes, int n_in,
                              void* d_out, int out_size, void* d_ws, size_t ws_size,
                              hipStream_t stream) {
    const float* x       = (const float*)d_in[0];
    const float* norm_w  = (const float*)d_in[1];
    const float* in_proj = (const float*)d_in[2];
    const float* conv_w  = (const float*)d_in[3];
    const float* conv_b  = (const float*)d_in[4];
    const float* x_proj  = (const float*)d_in[5];
    const float* dt_w    = (const float*)d_in[6];
    const float* dt_b    = (const float*)d_in[7];
    const float* a_log   = (const float*)d_in[8];
    const float* Dv      = (const float*)d_in[9];
    const float* out_w   = (const float*)d_in[10];
    float* out = (float*)d_out;

    char* ws = (char*)d_ws;
    u16*   xcp    = (u16*)(ws);                   //  8,413,184  padded conv input (bf16)
    u16*   hy     = (u16*)(ws + 8413184);         //  8,388,608  h -> xcc
    u16*   z_buf  = (u16*)(ws + 16801792);        //  8,388,608
    u16*   wt     = (u16*)(ws + 25190400);        // 33,554,432  conv_w^T bf16 (dead after conv)
    float* dlt    = (float*)(ws + 25190400);      // 16,777,216  aliases wt (after conv)
    u16*   y_buf  = (u16*)(ws + 41967616);        //  8,388,608  aliases wt tail
    u16*   inw    = (u16*)(ws + 58744832);        // 16,777,216  in_proj bf16 (dead after XZ)
    u16*   outw   = (u16*)(ws + 58744832);        //  8,388,608  out_proj bf16 (cast after XZ)
    u16*   xpw    = (u16*)(ws + 75522048);        //    524,288  x_proj bf16 padded
    float* dbc    = (float*)(ws + 76046336);      //    786,432  fp32 (T x 96)
    u16*   dbc64  = (u16*)(ws + 76832768);        //    262,144  bf16 delta cols
    u16*   dtw    = (u16*)(ws + 77094912);        //    131,072  dt_proj_w bf16
    // total 77,225,984 bytes

    transpose_w<<<dim3(32, 32, 4), 256, 0, stream>>>(conv_w, wt);
    pad_zero_k<<<48, 256, 0, stream>>>(xcp);
    xpw_k<<<1024, 256, 0, stream>>>(x_proj, xpw);
    cast_f2b_k<<<8192, 256, 0, stream>>>(in_proj, inw);
    cast_f2b_k<<<128, 256, 0, stream>>>(dt_w, dtw);
    rmsnorm_k<<<2048, 256, 0, stream>>>(x, norm_w, hy);

    // xz = h @ in_proj_w.T : split into xc (padded) and z
    gemm_bt<EPI_XZ, 1><<<dim3(16, 32), 256, 0, stream>>>(
        hy, inw, 2048, 0, 0, xcp, z_buf, nullptr, nullptr);

    // out_proj cast (reuses inw region; in_proj dead after XZ)
    cast_f2b_k<<<4096, 256, 0, stream>>>(out_w, outw);

    // conv (4 taps) + bias + silu -> xcc (hy region)
    gemm_bt<EPI_CONV, 4><<<dim3(16, 16), 256, 0, stream>>>(
        xcp, wt, 2048, H, (long)H * H, hy, nullptr, conv_b, nullptr);

    // dBC = xc @ x_proj_w.T (fp32 out + bf16 copy of delta cols)
    gemm_bt<EPI_DBC, 1><<<dim3(16, 1), 256, 0, stream>>>(
        hy, xpw, 2048, 0, 0, dbc, dbc64, nullptr, nullptr);

    // delta = softplus(dbc64 @ dt_proj_w.T + dt_b)  (K=64, fp32 out into dead wt region)
    gemm_bt<EPI_DELTA, 1><<<dim3(16, 16), 256, 0, stream>>>(
        dbc64, dtw, 64, 0, 0, dlt, nullptr, dt_b, nullptr);

    // chunked selective scan + gate, y -> y_buf
    scan_fused_k<<<4096, 256, 0, stream>>>(dlt, hy, dbc, a_log, Dv, z_buf, y_buf);

    // out = x + yg @ out_proj_w.T  (fp32 output)
    gemm_bt<EPI_OUT, 1><<<dim3(16, 16), 256, 0, stream>>>(
        y_buf, outw, 2048, 0, 0, out, nullptr, nullptr, x);
}